// Round 7
// baseline (624.833 us; speedup 1.0000x reference)
//
#include <hip/hip_runtime.h>
#include <cstdint>

// ---------------- problem constants ----------------
static constexpr int B_  = 8192;
static constexpr int NW_ = 192;                 // NS + NV

typedef __attribute__((ext_vector_type(8))) short s8v;
typedef __attribute__((ext_vector_type(4))) float f4v;
typedef __attribute__((ext_vector_type(2))) float f2v;
typedef __attribute__((ext_vector_type(4))) int i4v;
typedef __attribute__((ext_vector_type(4))) unsigned u4v;

#define DI __device__ __forceinline__

DI short f2bf_rne(float f) {
  unsigned u = __builtin_bit_cast(unsigned, f);
  u += 0x7FFFu + ((u >> 16) & 1u);               // round-to-nearest-even
  return (short)(u >> 16);
}
DI float bf2f(unsigned short h) {
  unsigned u = ((unsigned)h) << 16;
  return __builtin_bit_cast(float, u);
}
DI float ibitsf(int u) { return __builtin_bit_cast(float, u); }
DI float plo(int p) { return ibitsf(p << 16); }
DI float phi(int p) { return ibitsf((int)(p & 0xFFFF0000)); }
// pack bf16(lo), bf16(hi) with round-half-up: 2 adds + 1 v_perm
DI unsigned rpack(float lo, float hi) {
  unsigned ua = __builtin_bit_cast(unsigned, lo) + 0x8000u;
  unsigned ub = __builtin_bit_cast(unsigned, hi) + 0x8000u;
  return __builtin_amdgcn_perm(ub, ua, 0x07060302u);
}

DI f4v mfma16(s8v a, s8v b, f4v c) {
  return __builtin_amdgcn_mfma_f32_16x16x32_bf16(a, b, c, 0, 0, 0);
}

// ---------------- prep: scalar-path weights ----------------
// layout: wf[((s*2 + nh)*6 + nf)*512 + lane*8 + j]
//   k = s*32 + (lane>>4)*8 + j ; n = (nh*6+nf)*16 + (lane&15)
// -> per (s,nh) the wave's 6 frags are 6KB contiguous (immediate-offset friendly)
__global__ void prep_wsc(const float* __restrict__ w000, const float* __restrict__ w110,
                         short* __restrict__ wf) {
  int g = blockIdx.x * blockDim.x + threadIdx.x;  // 640*2*6*64 = 491520 threads
  int lane = g & 63;
  int rest = g >> 6;
  int nf = rest % 6;
  int rest2 = rest / 6;
  int nh = rest2 & 1;
  int s = rest2 >> 1;
  int n = (nh * 6 + nf) * 16 + (lane & 15);
  int kbase = s * 32 + ((lane >> 4) << 3);
  const float s000 = 1.0f / (128.0f * 1.41421356237f);
  const float s110 = 1.0f / (64.0f * 2.44948974968f);
  s8v o;
#pragma unroll
  for (int j = 0; j < 8; ++j) {
    int k = kbase + j;
    float v = (k < 16384) ? w000[(size_t)k * NW_ + n] * s000
                          : w110[(size_t)(k - 16384) * NW_ + n] * s110;
    o[j] = f2bf_rne(v);
  }
  *(s8v*)(wf + (((size_t)s * 2 + nh) * 6 + nf) * 512 + lane * 8) = o;
}

// ---------------- prep: vector-path weights ----------------
// layout: wf[(s*4 + nf)*512 + lane*8 + j]  (per s: 4 frags contiguous, 2KB)
__global__ void prep_wvec(const float* __restrict__ w011, const float* __restrict__ w111,
                          short* __restrict__ wf) {
  int g = blockIdx.x * blockDim.x + threadIdx.x;  // 384*4*64 = 98304 threads
  int lane = g & 63;
  int nf = (g >> 6) & 3;
  int s = g >> 8;
  int n = nf * 16 + (lane & 15);
  int kbase = s * 32 + ((lane >> 4) << 3);
  const float sv = 1.0f / 128.0f;
  s8v o;
#pragma unroll
  for (int j = 0; j < 8; ++j) {
    int k = kbase + j;
    float v = (k < 8192) ? w011[(size_t)k * 64 + n] * sv
                         : w111[(size_t)(k - 8192) * 64 + n] * sv;
    o[j] = f2bf_rne(v);
  }
  *(s8v*)(wf + ((size_t)s * 4 + nf) * 512 + lane * 8) = o;
}

// ---------------- shared LDS staging: 64 rows of x ----------------
#define X0_STRIDE 132
#define X1_STRIDE 200

DI void stage_x(const float* __restrict__ x, int b0, float* X0, unsigned short* X1) {
  const int t = threadIdx.x;            // 512 threads
  const int row = t >> 3, l8 = t & 7;
  const float* src = x + (size_t)(b0 + row) * 320;
#pragma unroll
  for (int j = 0; j < 4; ++j) {
    int c = l8 * 16 + j * 4;
    *(f4v*)(&X0[row * X0_STRIDE + c]) = *(const f4v*)(src + c);
  }
  float buf[24];
#pragma unroll
  for (int j = 0; j < 12; ++j) {
    f2v v = *(const f2v*)(src + 128 + l8 * 24 + j * 2);
    buf[2 * j] = v.x; buf[2 * j + 1] = v.y;
  }
#pragma unroll
  for (int i = 0; i < 3; ++i) {
    u4v o;
#pragma unroll
    for (int e = 0; e < 4; ++e)
      o[e] = rpack(buf[(2 * e) * 3 + i], buf[(2 * e + 1) * 3 + i]);
    *(u4v*)(&X1[row * X1_STRIDE + i * 64 + l8 * 8]) = o;
  }
}

// ---------------- A-fragment generators ----------------
DI s8v agen_x0v(const float* __restrict__ xr, float xu, int vb) {
  f4v v0 = *(const f4v*)(xr + vb);
  f4v v1 = *(const f4v*)(xr + vb + 4);
  u4v pa;
  pa[0] = rpack(xu * v0.x, xu * v0.y);
  pa[1] = rpack(xu * v0.z, xu * v0.w);
  pa[2] = rpack(xu * v1.x, xu * v1.y);
  pa[3] = rpack(xu * v1.z, xu * v1.w);
  return __builtin_bit_cast(s8v, pa);
}
DI s8v agen_dotsv(const unsigned short* __restrict__ x1r, const float* us, int vb) {
  float sm[8] = {0.f, 0.f, 0.f, 0.f, 0.f, 0.f, 0.f, 0.f};
#pragma unroll
  for (int i = 0; i < 3; ++i) {
    i4v p = *(const i4v*)(x1r + i * 64 + vb);
#pragma unroll
    for (int m = 0; m < 4; ++m) {
      sm[2 * m]     += us[i] * plo(p[m]);
      sm[2 * m + 1] += us[i] * phi(p[m]);
    }
  }
  u4v pa;
  pa[0] = rpack(sm[0], sm[1]);
  pa[1] = rpack(sm[2], sm[3]);
  pa[2] = rpack(sm[4], sm[5]);
  pa[3] = rpack(sm[6], sm[7]);
  return __builtin_bit_cast(s8v, pa);
}

// B-frag loaders — always called unconditionally (SROA-safe)
DI void loadB3(s8v* dst, const short* __restrict__ p) {
#pragma unroll
  for (int nf = 0; nf < 3; ++nf) dst[nf] = *(const s8v*)(p + nf * 512);
}
DI void loadB2(s8v* dst, const short* __restrict__ p) {
#pragma unroll
  for (int nf = 0; nf < 2; ++nf) dst[nf] = *(const s8v*)(p + nf * 512);
}

DI void mfmaH_sc(f4v (&acc)[2][6], s8v a0, s8v a1, const s8v* b, int off) {
#pragma unroll
  for (int nf = 0; nf < 3; ++nf) {
    acc[0][off + nf] = mfma16(a0, b[nf], acc[0][off + nf]);
    acc[1][off + nf] = mfma16(a1, b[nf], acc[1][off + nf]);
  }
}
DI void mfmaH_ve(f4v (&acc)[3][4], const s8v* a, const s8v* b, int off) {
#pragma unroll
  for (int ip = 0; ip < 3; ++ip)
#pragma unroll
    for (int nf = 0; nf < 2; ++nf)
      acc[ip][off + nf] = mfma16(a[ip], b[nf], acc[ip][off + nf]);
}

// ---------------- scalar-path GEMM: C[8192,192] += A(gen) * Wsc ----------------
// grid 512 = 128 mt x 4 kb; block 64 rows x 192 cols; 8 waves = mg2 x nh2 x kh2
// wave = 2 m-frags x 6 n-frags (12 MFMA/step); chunk c = kb*2+kh: 64 x0 + 16 dots steps
__global__ __launch_bounds__(512, 4)
void gemm_sc(const float* __restrict__ x, const short* __restrict__ wf,
             float* __restrict__ acc_out) {
  __shared__ float X0[64 * X0_STRIDE];
  __shared__ unsigned short X1[64 * X1_STRIDE];
  const int kb = blockIdx.x & 3;
  const int b0 = (blockIdx.x >> 2) * 64;

  stage_x(x, b0, X0, X1);
  __syncthreads();

  const int t0 = threadIdx.x;
  const int w = t0 >> 6, lane = t0 & 63;
  const int mg = w & 1, nh = (w >> 1) & 1, kh = w >> 2;
  const int c = kb * 2 + kh;            // chunk 0..7
  const int q = lane >> 4, r = lane & 15, q8 = q * 8;
  const int rowA = mg * 32 + r;
  const float* x0A = &X0[rowA * X0_STRIDE];
  const float* x0B = &X0[(rowA + 16) * X0_STRIDE];
  const unsigned short* x1A = &X1[rowA * X1_STRIDE];
  const unsigned short* x1B = &X1[(rowA + 16) * X1_STRIDE];

  f4v acc[2][6];
#pragma unroll
  for (int f = 0; f < 2; ++f)
#pragma unroll
    for (int nf = 0; nf < 6; ++nf) acc[f][nf] = f4v{0.f, 0.f, 0.f, 0.f};

  s8v b0r[3], b1r[3];

  // ---- region 1: x0 outer product, 64 steps, s in [c*64, +64) ----
  {
    const int u0 = c * 16;
    const short* wp = wf + (((size_t)(c * 64) * 2 + nh) * 6) * 512 + lane * 8;  // FIX: +lane*8
    loadB3(b0r, wp);
    for (int g = 0; g < 16; ++g) {
      const float xuA = x0A[u0 + g];
      const float xuB = x0B[u0 + g];
#pragma unroll
      for (int j = 0; j < 4; ++j) {
        const int vb = j * 32 + q8;
        loadB3(b1r, wp + 1536);               // frags 3-5 of this step
        s8v a0 = agen_x0v(x0A, xuA, vb);
        s8v a1 = agen_x0v(x0B, xuB, vb);
        mfmaH_sc(acc, a0, a1, b0r, 0);
        const short* wpn = wp + 6144;         // next step (in-bounds: s<=512)
        loadB3(b0r, wpn);                     // frags 0-2 of next step
        mfmaH_sc(acc, a0, a1, b1r, 3);
        wp = wpn;
      }
    }
  }

  // ---- region 2: x1-dots, 16 steps, s in [512 + c*16, +16) ----
  {
    const int u0 = c * 8;
    const short* wp = wf + (((size_t)(512 + c * 16) * 2 + nh) * 6) * 512 + lane * 8;  // FIX
    loadB3(b0r, wp);
    for (int g = 0; g < 8; ++g) {
      const int u = u0 + g;
      float usA[3], usB[3];
#pragma unroll
      for (int i = 0; i < 3; ++i) {
        usA[i] = bf2f(x1A[i * 64 + u]);
        usB[i] = bf2f(x1B[i * 64 + u]);
      }
#pragma unroll
      for (int j = 0; j < 2; ++j) {
        const int vb = j * 32 + q8;
        loadB3(b1r, wp + 1536);
        s8v a0 = agen_dotsv(x1A, usA, vb);
        s8v a1 = agen_dotsv(x1B, usB, vb);
        mfmaH_sc(acc, a0, a1, b0r, 0);
        const short* wpn = wp + ((g * 2 + j + 1 < 16) ? 6144 : 0);  // guard OOB at end
        loadB3(b0r, wpn);
        mfmaH_sc(acc, a0, a1, b1r, 3);
        wp = wpn;
      }
    }
  }

#pragma unroll
  for (int f = 0; f < 2; ++f)
#pragma unroll
    for (int nf = 0; nf < 6; ++nf) {
      int n = (nh * 6 + nf) * 16 + r;
#pragma unroll
      for (int reg = 0; reg < 4; ++reg) {
        int rowo = b0 + mg * 32 + f * 16 + q * 4 + reg;
        atomicAdd(&acc_out[(size_t)rowo * NW_ + n], acc[f][nf][reg]);
      }
    }
}

// ---------------- vector-path GEMM: C[3*8192, 64] += A(gen) * Wvec ----------------
// grid 512 = 128 mt x 4 kb; block 64 rows x 3 planes x 64 cols; 8 waves = mg4 x kh2
// wave = 1 m-frag x 3 planes x 4 n-frags (12 MFMA/step); chunk c: 32 + 16 steps
__global__ __launch_bounds__(512, 4)
void gemm_vec(const float* __restrict__ x, const short* __restrict__ wf,
              float* __restrict__ acc_out) {
  __shared__ float X0[64 * X0_STRIDE];
  __shared__ unsigned short X1[64 * X1_STRIDE];
  const int kb = blockIdx.x & 3;
  const int b0 = (blockIdx.x >> 2) * 64;

  stage_x(x, b0, X0, X1);
  __syncthreads();

  const int t0 = threadIdx.x;
  const int w = t0 >> 6, lane = t0 & 63;
  const int mg = w & 3, kh = w >> 2;
  const int c = kb * 2 + kh;            // chunk 0..7
  const int q = lane >> 4, r = lane & 15, q8 = q * 8;
  const int row = mg * 16 + r;
  const float* x0r = &X0[row * X0_STRIDE];
  const unsigned short* x1r = &X1[row * X1_STRIDE];

  f4v acc[3][4];
#pragma unroll
  for (int ip = 0; ip < 3; ++ip)
#pragma unroll
    for (int nf = 0; nf < 4; ++nf) acc[ip][nf] = f4v{0.f, 0.f, 0.f, 0.f};

  s8v b0r[2], b1r[2];
  s8v a[3];

  // ---- region 1: x0 * x1[ip], 32 steps, s in [c*32, +32) ----
  {
    const int u0 = c * 16;
    const short* wp = wf + (size_t)(c * 32) * 2048 + lane * 8;   // FIX: +lane*8
    loadB2(b0r, wp);
    for (int g = 0; g < 16; ++g) {
      const float xu = x0r[u0 + g];
#pragma unroll
      for (int j = 0; j < 2; ++j) {
        const int vb = j * 32 + q8;
        loadB2(b1r, wp + 1024);               // frags 2-3
#pragma unroll
        for (int i = 0; i < 3; ++i) {
          i4v p = *(const i4v*)(x1r + i * 64 + vb);
          u4v pa;
#pragma unroll
          for (int m = 0; m < 4; ++m)
            pa[m] = rpack(xu * plo(p[m]), xu * phi(p[m]));
          a[i] = __builtin_bit_cast(s8v, pa);
        }
        mfmaH_ve(acc, a, b0r, 0);
        const short* wpn = wp + 2048;         // in-bounds: s<=256
        loadB2(b0r, wpn);
        mfmaH_ve(acc, a, b1r, 2);
        wp = wpn;
      }
    }
  }

  // ---- region 2: cross products, 16 steps, s in [256 + c*16, +16) ----
  {
    const int u0 = c * 8;
    const short* wp = wf + (size_t)(256 + c * 16) * 2048 + lane * 8;  // FIX
    loadB2(b0r, wp);
    for (int g = 0; g < 8; ++g) {
      const int u = u0 + g;
      float us[3];
#pragma unroll
      for (int i = 0; i < 3; ++i) us[i] = bf2f(x1r[i * 64 + u]);
#pragma unroll
      for (int j = 0; j < 2; ++j) {
        const int vb = j * 32 + q8;
        loadB2(b1r, wp + 1024);
        i4v p[3];
#pragma unroll
        for (int i = 0; i < 3; ++i) p[i] = *(const i4v*)(x1r + i * 64 + vb);
#pragma unroll
        for (int ip = 0; ip < 3; ++ip) {
          const int i1 = (ip + 1) % 3, i2 = (ip + 2) % 3;
          u4v pa;
#pragma unroll
          for (int m = 0; m < 4; ++m) {
            float lo = us[i1] * plo(p[i2][m]) - us[i2] * plo(p[i1][m]);
            float hi = us[i1] * phi(p[i2][m]) - us[i2] * phi(p[i1][m]);
            pa[m] = rpack(lo, hi);
          }
          a[ip] = __builtin_bit_cast(s8v, pa);
        }
        mfmaH_ve(acc, a, b0r, 0);
        const short* wpn = wp + ((g * 2 + j + 1 < 16) ? 2048 : 0);
        loadB2(b0r, wpn);
        mfmaH_ve(acc, a, b1r, 2);
        wp = wpn;
      }
    }
  }

#pragma unroll
  for (int ip = 0; ip < 3; ++ip)
#pragma unroll
    for (int nf = 0; nf < 4; ++nf) {
      int n = nf * 16 + r;
#pragma unroll
      for (int reg = 0; reg < 4; ++reg) {
        int rowo = ip * B_ + b0 + mg * 16 + q * 4 + reg;
        atomicAdd(&acc_out[(size_t)rowo * 64 + n], acc[ip][nf][reg]);
      }
    }
}

// ---------------- epilogue: silu / sigmoid-gating, interleaved output ----------------
__global__ void epilogue(const float* __restrict__ sc, const float* __restrict__ ve,
                         float* __restrict__ out) {
  int t = blockIdx.x * blockDim.x + threadIdx.x;  // B*192 threads exactly
  int b = t / NW_, c = t % NW_;
  float v = sc[t];
  float sg = 1.0f / (1.0f + __expf(-v));
  if (c < 128) {
    out[(size_t)b * 320 + c] = v * sg;            // silu
  } else {
    int w = c - 128;
#pragma unroll
    for (int i = 0; i < 3; ++i) {
      float vv = ve[((size_t)i * B_ + b) * 64 + w];
      out[(size_t)b * 320 + 128 + w * 3 + i] = vv * sg;
    }
  }
}

// ---------------- launch ----------------
extern "C" void kernel_launch(void* const* d_in, const int* in_sizes, int n_in,
                              void* d_out, int out_size, void* d_ws, size_t ws_size,
                              hipStream_t stream) {
  const float* x    = (const float*)d_in[0];
  const float* w000 = (const float*)d_in[1];
  const float* w110 = (const float*)d_in[2];
  const float* w011 = (const float*)d_in[3];
  const float* w111 = (const float*)d_in[4];
  float* out = (float*)d_out;

  char* ws = (char*)d_ws;
  float* acc_sc = (float*)ws;                     // 8192*192*4  = 6,291,456 B
  float* acc_ve = (float*)(ws + 6291456);         // 3*8192*64*4 = 6,291,456 B
  short* wsc    = (short*)(ws + 12582912);        // 20480*192*2 = 7,864,320 B
  short* wve    = (short*)(ws + 20447232);        // 12288*64*2  = 1,572,864 B

  (void)hipMemsetAsync(acc_sc, 0, 2 * 6291456, stream);  // zero both accumulators
  prep_wsc <<<1920, 256, 0, stream>>>(w000, w110, wsc);
  prep_wvec<<<384,  256, 0, stream>>>(w011, w111, wve);
  gemm_sc  <<<512, 512, 0, stream>>>(x, wsc, acc_sc);
  gemm_vec <<<512, 512, 0, stream>>>(x, wve, acc_ve);
  epilogue <<<6144, 256, 0, stream>>>(acc_sc, acc_ve, out);
}

// Round 8
// 289.690 us; speedup vs baseline: 2.1569x; 2.1569x over previous
//
#include <hip/hip_runtime.h>
#include <cstdint>

// ---------------- problem constants ----------------
static constexpr int B_  = 8192;
static constexpr int NW_ = 192;                 // NS + NV

typedef __attribute__((ext_vector_type(8))) _Float16 h8v;
typedef __attribute__((ext_vector_type(2))) _Float16 h2v;
typedef __attribute__((ext_vector_type(4))) float f4v;
typedef __attribute__((ext_vector_type(2))) float f2v;
typedef __attribute__((ext_vector_type(4))) unsigned u4v;

#define DI __device__ __forceinline__

DI h2v uh(unsigned u) { return __builtin_bit_cast(h2v, u); }
DI unsigned hu(h2v h) { return __builtin_bit_cast(unsigned, h); }
DI h2v hsplat(unsigned short bits) {
  _Float16 v = __builtin_bit_cast(_Float16, bits);
  h2v t; t.x = v; t.y = v; return t;
}
DI unsigned hpack(float lo, float hi) {       // 2x f32 -> packed f16 (RNE, prep/staging only)
  h2v t; t.x = (_Float16)lo; t.y = (_Float16)hi;
  return __builtin_bit_cast(unsigned, t);
}
DI short f2h_bits(float f) { return __builtin_bit_cast(short, (_Float16)f); }

DI f4v mfma16h(h8v a, h8v b, f4v c) {
  return __builtin_amdgcn_mfma_f32_16x16x32_f16(a, b, c, 0, 0, 0);
}

// ---------------- prep: scalar-path weights (f16 frags) ----------------
// layout: wf[((s*2 + nh)*6 + nf)*512 + lane*8 + j]     [verified correct in r7]
//   k = s*32 + (lane>>4)*8 + j ; n = (nh*6+nf)*16 + (lane&15)
__global__ void prep_wsc(const float* __restrict__ w000, const float* __restrict__ w110,
                         short* __restrict__ wf) {
  int g = blockIdx.x * blockDim.x + threadIdx.x;  // 640*2*6*64 = 491520 threads
  int lane = g & 63;
  int rest = g >> 6;
  int nf = rest % 6;
  int rest2 = rest / 6;
  int nh = rest2 & 1;
  int s = rest2 >> 1;
  int n = (nh * 6 + nf) * 16 + (lane & 15);
  int kbase = s * 32 + ((lane >> 4) << 3);
  const float s000 = 1.0f / (128.0f * 1.41421356237f);   // (1/N0) * inv_sqrt2
  const float s110 = 1.0f / (64.0f * 2.44948974968f);    // (1/(N1*sqrt3)) * inv_sqrt2
  short o[8];
#pragma unroll
  for (int j = 0; j < 8; ++j) {
    int k = kbase + j;
    float v = (k < 16384) ? w000[(size_t)k * NW_ + n] * s000
                          : w110[(size_t)(k - 16384) * NW_ + n] * s110;
    o[j] = f2h_bits(v);
  }
  *(h8v*)(wf + (((size_t)s * 2 + nh) * 6 + nf) * 512 + lane * 8) = *(h8v*)o;
}

// ---------------- prep: vector-path weights (f16 frags) ----------------
// layout: wf[(s*4 + nf)*512 + lane*8 + j]               [verified correct in r7]
__global__ void prep_wvec(const float* __restrict__ w011, const float* __restrict__ w111,
                          short* __restrict__ wf) {
  int g = blockIdx.x * blockDim.x + threadIdx.x;  // 384*4*64 = 98304 threads
  int lane = g & 63;
  int nf = (g >> 6) & 3;
  int s = g >> 8;
  int n = nf * 16 + (lane & 15);
  int kbase = s * 32 + ((lane >> 4) << 3);
  const float sv = 1.0f / 128.0f;  // both v011 and v111 total scales reduce to 1/128
  short o[8];
#pragma unroll
  for (int j = 0; j < 8; ++j) {
    int k = kbase + j;
    float v = (k < 8192) ? w011[(size_t)k * 64 + n] * sv
                         : w111[(size_t)(k - 8192) * 64 + n] * sv;
    o[j] = f2h_bits(v);
  }
  *(h8v*)(wf + ((size_t)s * 4 + nf) * 512 + lane * 8) = *(h8v*)o;
}

// ---------------- shared LDS staging: 64 rows of x, all f16 ----------------
// X0H[row][c]        f16, stride 136 halves (272 B, 16B-aligned rows)
// X1 [row][i*64+v]   f16, stride 200 halves (400 B)
#define X0H_STRIDE 136
#define X1_STRIDE  200

DI void stage_x(const float* __restrict__ x, int b0,
                unsigned short* X0H, unsigned short* X1) {
  const int t = threadIdx.x;            // 512 threads
  const int row = t >> 3, l8 = t & 7;
  const float* src = x + (size_t)(b0 + row) * 320;
  // x0: 16 consecutive floats per thread -> 8 packed f16 pairs -> 2 b128 writes
  unsigned o[8];
#pragma unroll
  for (int j = 0; j < 4; ++j) {
    f4v v = *(const f4v*)(src + l8 * 16 + j * 4);
    o[2 * j]     = hpack(v.x, v.y);
    o[2 * j + 1] = hpack(v.z, v.w);
  }
  *(u4v*)(&X0H[row * X0H_STRIDE + l8 * 16])     = u4v{o[0], o[1], o[2], o[3]};
  *(u4v*)(&X0H[row * X0H_STRIDE + l8 * 16 + 8]) = u4v{o[4], o[5], o[6], o[7]};
  // x1: 24 consecutive floats, de-interleave into 3 planes, one b128 per plane
  float buf[24];
#pragma unroll
  for (int j = 0; j < 12; ++j) {
    f2v v = *(const f2v*)(src + 128 + l8 * 24 + j * 2);
    buf[2 * j] = v.x; buf[2 * j + 1] = v.y;
  }
#pragma unroll
  for (int i = 0; i < 3; ++i) {
    u4v w;
#pragma unroll
    for (int e = 0; e < 4; ++e)
      w[e] = hpack(buf[(2 * e) * 3 + i], buf[(2 * e + 1) * 3 + i]);
    *(u4v*)(&X1[row * X1_STRIDE + i * 64 + l8 * 8]) = w;
  }
}

// ---------------- A-fragment generators (packed f16 math) ----------------
// x0 outer product: 4 v_pk_mul_f16
DI h8v agen_x0h(const unsigned short* __restrict__ x0r, h2v xu2, int vb) {
  u4v p = *(const u4v*)(x0r + vb);
  u4v pa;
#pragma unroll
  for (int m = 0; m < 4; ++m) pa[m] = hu(uh(p[m]) * xu2);
  return __builtin_bit_cast(h8v, pa);
}
// x1 dot3: 3 b128 loads + 12 pk_fma
DI h8v agen_dotsh(const unsigned short* __restrict__ x1r, const h2v* us, int vb) {
  u4v p0 = *(const u4v*)(x1r + vb);
  u4v p1 = *(const u4v*)(x1r + 64 + vb);
  u4v p2 = *(const u4v*)(x1r + 128 + vb);
  u4v pa;
#pragma unroll
  for (int m = 0; m < 4; ++m) {
    h2v s = uh(p0[m]) * us[0];
    s = s + uh(p1[m]) * us[1];
    s = s + uh(p2[m]) * us[2];
    pa[m] = hu(s);
  }
  return __builtin_bit_cast(h8v, pa);
}

// B-frag loaders (load-at-use, r2 style — no ping-pong, no spill)
DI void loadB6(h8v* dst, const short* __restrict__ p) {
#pragma unroll
  for (int nf = 0; nf < 6; ++nf) dst[nf] = *(const h8v*)(p + nf * 512);
}
DI void loadB4(h8v* dst, const short* __restrict__ p) {
#pragma unroll
  for (int nf = 0; nf < 4; ++nf) dst[nf] = *(const h8v*)(p + nf * 512);
}

// ---------------- scalar-path GEMM: C[8192,192] += A(gen) * Wsc ----------------
// grid 512 = 128 mt x 4 kb; block 64 rows x 192 cols; 8 waves = mg2 x nh2 x kh2
// wave = 2 m-frags x 6 n-frags (12 MFMA/step); chunk c = kb*2+kh: 64 x0 + 16 dots steps
__global__ __launch_bounds__(512, 4)
void gemm_sc(const float* __restrict__ x, const short* __restrict__ wf,
             float* __restrict__ acc_out) {
  __shared__ unsigned short X0H[64 * X0H_STRIDE];
  __shared__ unsigned short X1[64 * X1_STRIDE];
  const int kb = blockIdx.x & 3;
  const int b0 = (blockIdx.x >> 2) * 64;

  stage_x(x, b0, X0H, X1);
  __syncthreads();

  const int t0 = threadIdx.x;
  const int w = t0 >> 6, lane = t0 & 63;
  const int mg = w & 1, nh = (w >> 1) & 1, kh = w >> 2;
  const int c = kb * 2 + kh;            // chunk 0..7
  const int q = lane >> 4, r = lane & 15, q8 = q * 8;
  const int rowA = mg * 32 + r;
  const unsigned short* x0A = &X0H[rowA * X0H_STRIDE];
  const unsigned short* x0B = &X0H[(rowA + 16) * X0H_STRIDE];
  const unsigned short* x1A = &X1[rowA * X1_STRIDE];
  const unsigned short* x1B = &X1[(rowA + 16) * X1_STRIDE];

  f4v acc[2][6];
#pragma unroll
  for (int f = 0; f < 2; ++f)
#pragma unroll
    for (int nf = 0; nf < 6; ++nf) acc[f][nf] = f4v{0.f, 0.f, 0.f, 0.f};

  // ---- region 1: x0 outer product, 64 steps, s in [c*64, +64) ----
  {
    const int u0 = c * 16;
    const short* wp = wf + (((size_t)(c * 64) * 2 + nh) * 6) * 512 + lane * 8;
    for (int g = 0; g < 16; ++g) {
      h2v xuA = hsplat(x0A[u0 + g]);
      h2v xuB = hsplat(x0B[u0 + g]);
#pragma unroll
      for (int j = 0; j < 4; ++j) {
        h8v b[6];
        loadB6(b, wp);
        const int vb = j * 32 + q8;
        h8v a0 = agen_x0h(x0A, xuA, vb);
        h8v a1 = agen_x0h(x0B, xuB, vb);
#pragma unroll
        for (int nf = 0; nf < 6; ++nf) {
          acc[0][nf] = mfma16h(a0, b[nf], acc[0][nf]);
          acc[1][nf] = mfma16h(a1, b[nf], acc[1][nf]);
        }
        wp += 6144;                      // one K-step (2 nh x 6 frags x 512)
      }
    }
  }

  // ---- region 2: x1-dots, 16 steps, s in [512 + c*16, +16) ----
  {
    const int u0 = c * 8;
    const short* wp = wf + (((size_t)(512 + c * 16) * 2 + nh) * 6) * 512 + lane * 8;
    for (int g = 0; g < 8; ++g) {
      const int u = u0 + g;
      h2v usA[3], usB[3];
#pragma unroll
      for (int i = 0; i < 3; ++i) {
        usA[i] = hsplat(x1A[i * 64 + u]);
        usB[i] = hsplat(x1B[i * 64 + u]);
      }
#pragma unroll
      for (int j = 0; j < 2; ++j) {
        h8v b[6];
        loadB6(b, wp);
        const int vb = j * 32 + q8;
        h8v a0 = agen_dotsh(x1A, usA, vb);
        h8v a1 = agen_dotsh(x1B, usB, vb);
#pragma unroll
        for (int nf = 0; nf < 6; ++nf) {
          acc[0][nf] = mfma16h(a0, b[nf], acc[0][nf]);
          acc[1][nf] = mfma16h(a1, b[nf], acc[1][nf]);
        }
        wp += 6144;
      }
    }
  }

#pragma unroll
  for (int f = 0; f < 2; ++f)
#pragma unroll
    for (int nf = 0; nf < 6; ++nf) {
      int n = (nh * 6 + nf) * 16 + r;
#pragma unroll
      for (int reg = 0; reg < 4; ++reg) {
        int rowo = b0 + mg * 32 + f * 16 + q * 4 + reg;
        atomicAdd(&acc_out[(size_t)rowo * NW_ + n], acc[f][nf][reg]);
      }
    }
}

// ---------------- vector-path GEMM: C[3*8192, 64] += A(gen) * Wvec ----------------
// grid 512 = 128 mt x 4 kb; block 64 rows x 3 planes x 64 cols; 8 waves = mg4 x kh2
// wave = 1 m-frag x 3 planes x 4 n-frags (12 MFMA/step); chunk c: 32 + 16 steps
__global__ __launch_bounds__(512, 4)
void gemm_vec(const float* __restrict__ x, const short* __restrict__ wf,
              float* __restrict__ acc_out) {
  __shared__ unsigned short X0H[64 * X0H_STRIDE];
  __shared__ unsigned short X1[64 * X1_STRIDE];
  const int kb = blockIdx.x & 3;
  const int b0 = (blockIdx.x >> 2) * 64;

  stage_x(x, b0, X0H, X1);
  __syncthreads();

  const int t0 = threadIdx.x;
  const int w = t0 >> 6, lane = t0 & 63;
  const int mg = w & 3, kh = w >> 2;
  const int c = kb * 2 + kh;            // chunk 0..7
  const int q = lane >> 4, r = lane & 15, q8 = q * 8;
  const int row = mg * 16 + r;
  const unsigned short* x0r = &X0H[row * X0H_STRIDE];
  const unsigned short* x1r = &X1[row * X1_STRIDE];

  f4v acc[3][4];
#pragma unroll
  for (int ip = 0; ip < 3; ++ip)
#pragma unroll
    for (int nf = 0; nf < 4; ++nf) acc[ip][nf] = f4v{0.f, 0.f, 0.f, 0.f};

  // ---- region 1: x0 * x1[ip], 32 steps, s in [c*32, +32) ----
  {
    const int u0 = c * 16;
    const short* wp = wf + (size_t)(c * 32) * 2048 + lane * 8;
    for (int g = 0; g < 16; ++g) {
      h2v xu2 = hsplat(x0r[u0 + g]);
#pragma unroll
      for (int j = 0; j < 2; ++j) {
        h8v b[4];
        loadB4(b, wp);
        const int vb = j * 32 + q8;
        h8v a[3];
#pragma unroll
        for (int i = 0; i < 3; ++i) {
          u4v p = *(const u4v*)(x1r + i * 64 + vb);
          u4v pa;
#pragma unroll
          for (int m = 0; m < 4; ++m) pa[m] = hu(uh(p[m]) * xu2);
          a[i] = __builtin_bit_cast(h8v, pa);
        }
#pragma unroll
        for (int ip = 0; ip < 3; ++ip)
#pragma unroll
          for (int nf = 0; nf < 4; ++nf)
            acc[ip][nf] = mfma16h(a[ip], b[nf], acc[ip][nf]);
        wp += 2048;                      // one K-step (4 frags x 512)
      }
    }
  }

  // ---- region 2: cross products, 16 steps, s in [256 + c*16, +16) ----
  {
    const int u0 = c * 8;
    const short* wp = wf + (size_t)(256 + c * 16) * 2048 + lane * 8;
    for (int g = 0; g < 8; ++g) {
      const int u = u0 + g;
      h2v us[3];
#pragma unroll
      for (int i = 0; i < 3; ++i) us[i] = hsplat(x1r[i * 64 + u]);
#pragma unroll
      for (int j = 0; j < 2; ++j) {
        h8v b[4];
        loadB4(b, wp);
        const int vb = j * 32 + q8;
        u4v p[3];
#pragma unroll
        for (int i = 0; i < 3; ++i) p[i] = *(const u4v*)(x1r + i * 64 + vb);
        h8v a[3];
#pragma unroll
        for (int ip = 0; ip < 3; ++ip) {
          const int i1 = (ip + 1) % 3, i2 = (ip + 2) % 3;
          u4v pa;
#pragma unroll
          for (int m = 0; m < 4; ++m)
            pa[m] = hu(uh(p[i2][m]) * us[i1] - uh(p[i1][m]) * us[i2]);
          a[ip] = __builtin_bit_cast(h8v, pa);
        }
#pragma unroll
        for (int ip = 0; ip < 3; ++ip)
#pragma unroll
          for (int nf = 0; nf < 4; ++nf)
            acc[ip][nf] = mfma16h(a[ip], b[nf], acc[ip][nf]);
        wp += 2048;
      }
    }
  }

#pragma unroll
  for (int ip = 0; ip < 3; ++ip)
#pragma unroll
    for (int nf = 0; nf < 4; ++nf) {
      int n = nf * 16 + r;
#pragma unroll
      for (int reg = 0; reg < 4; ++reg) {
        int rowo = ip * B_ + b0 + mg * 16 + q * 4 + reg;
        atomicAdd(&acc_out[(size_t)rowo * 64 + n], acc[ip][nf][reg]);
      }
    }
}

// ---------------- epilogue: silu / sigmoid-gating, interleaved output ----------------
__global__ void epilogue(const float* __restrict__ sc, const float* __restrict__ ve,
                         float* __restrict__ out) {
  int t = blockIdx.x * blockDim.x + threadIdx.x;  // B*192 threads exactly
  int b = t / NW_, c = t % NW_;
  float v = sc[t];
  float sg = 1.0f / (1.0f + __expf(-v));
  if (c < 128) {
    out[(size_t)b * 320 + c] = v * sg;            // silu
  } else {
    int w = c - 128;
#pragma unroll
    for (int i = 0; i < 3; ++i) {
      float vv = ve[((size_t)i * B_ + b) * 64 + w];
      out[(size_t)b * 320 + 128 + w * 3 + i] = vv * sg;
    }
  }
}

// ---------------- launch ----------------
extern "C" void kernel_launch(void* const* d_in, const int* in_sizes, int n_in,
                              void* d_out, int out_size, void* d_ws, size_t ws_size,
                              hipStream_t stream) {
  const float* x    = (const float*)d_in[0];
  const float* w000 = (const float*)d_in[1];
  const float* w110 = (const float*)d_in[2];
  const float* w011 = (const float*)d_in[3];
  const float* w111 = (const float*)d_in[4];
  float* out = (float*)d_out;

  char* ws = (char*)d_ws;
  float* acc_sc = (float*)ws;                     // 8192*192*4  = 6,291,456 B
  float* acc_ve = (float*)(ws + 6291456);         // 3*8192*64*4 = 6,291,456 B
  short* wsc    = (short*)(ws + 12582912);        // 20480*192*2 = 7,864,320 B
  short* wve    = (short*)(ws + 20447232);        // 12288*64*2  = 1,572,864 B

  (void)hipMemsetAsync(acc_sc, 0, 2 * 6291456, stream);  // zero both accumulators
  prep_wsc <<<1920, 256, 0, stream>>>(w000, w110, wsc);
  prep_wvec<<<384,  256, 0, stream>>>(w011, w111, wve);
  gemm_sc  <<<512, 512, 0, stream>>>(x, wsc, acc_sc);
  gemm_vec <<<512, 512, 0, stream>>>(x, wve, acc_ve);
  epilogue <<<6144, 256, 0, stream>>>(acc_sc, acc_ve, out);
}